// Round 11
// baseline (132.251 us; speedup 1.0000x reference)
//
#include <hip/hip_runtime.h>
#include <hip/hip_bf16.h>

#define B_SZ 16384
#define E_SZ 128
#define H_SZ 256
#define A_SZ 20
#define K_SZ 384           // H + E
#define BH   (B_SZ * H_SZ) // 4194304

typedef __attribute__((ext_vector_type(8))) short  short8v;
typedef __attribute__((ext_vector_type(4))) float  f32x4;
typedef __attribute__((ext_vector_type(2))) float  f32x2;
typedef __attribute__((ext_vector_type(4))) unsigned short ushort4v;
typedef __attribute__((ext_vector_type(2))) unsigned short ushort2v;

__device__ __forceinline__ unsigned short f2bf(float f) {
    union { float f; unsigned u; } v; v.f = f;
    unsigned r = v.u + 0x7fffu + ((v.u >> 16) & 1u);   // RNE
    return (unsigned short)(r >> 16);
}

__device__ __forceinline__ float wsum(float v) {
    #pragma unroll
    for (int off = 32; off > 0; off >>= 1) v += __shfl_xor(v, off, 64);
    return v;
}

// fast epilogue math: v_exp (TRANS pipe) + v_rcp, ~6 instr vs ~50 for libm
__device__ __forceinline__ float tanh_fast(float x) {
    float cx = fminf(fmaxf(x, -15.f), 15.f);
    float t  = __expf(2.f * cx);                  // e^{2x} <= e^30, no inf
    return (t - 1.f) * __builtin_amdgcn_rcpf(t + 1.f);
}
__device__ __forceinline__ float sigm_fast(float x) {
    float cx = fminf(fmaxf(x, -30.f), 30.f);
    return __builtin_amdgcn_rcpf(1.f + __expf(-cx));
}

struct Ptr8 { const float* p[8]; };

// ---------------- Kernel 1: attention + bf16 pack: Hb=[h], A1x=[x1], A2x=[x2m]
__global__ __launch_bounds__(256) void attn_pack(
    const float* __restrict__ x1, const float* __restrict__ x2,
    const float* __restrict__ h,  const float* __restrict__ wa,
    unsigned short* __restrict__ Hb, unsigned short* __restrict__ A1x,
    unsigned short* __restrict__ A2x)
{
    const int row  = blockIdx.x * 4 + (threadIdx.x >> 6);
    const int lane = threadIdx.x & 63;

    const f32x4 hv   = *(const f32x4*)(h  + (size_t)row * H_SZ + 4 * lane);
    const f32x2 x1v  = *(const f32x2*)(x1 + (size_t)row * E_SZ + 2 * lane);
    const f32x4 wah  = *(const f32x4*)(wa + 4 * lane);
    const f32x2 wax1 = *(const f32x2*)(wa + H_SZ + 2 * lane);
    const f32x2 wax2 = *(const f32x2*)(wa + H_SZ + E_SZ + 2 * lane);

    float base = hv.x * wah.x + hv.y * wah.y + hv.z * wah.z + hv.w * wah.w
               + x1v.x * wax1.x + x1v.y * wax1.y;

    f32x2 xv[A_SZ];
    float sp[A_SZ];
    const float* x2r = x2 + (size_t)row * A_SZ * E_SZ;
    #pragma unroll
    for (int a = 0; a < A_SZ; ++a) {
        xv[a] = *(const f32x2*)(x2r + a * E_SZ + 2 * lane);
        sp[a] = xv[a].x * wax2.x + xv[a].y * wax2.y;
    }

    base = wsum(base);
    #pragma unroll
    for (int a = 0; a < A_SZ; ++a) sp[a] = wsum(sp[a]) + base;

    float mx = sp[0];
    #pragma unroll
    for (int a = 1; a < A_SZ; ++a) mx = fmaxf(mx, sp[a]);
    float s = 0.0f;
    #pragma unroll
    for (int a = 0; a < A_SZ; ++a) { sp[a] = __expf(sp[a] - mx); s += sp[a]; }
    const float inv = 1.0f / s;

    float m0 = 0.0f, m1 = 0.0f;
    #pragma unroll
    for (int a = 0; a < A_SZ; ++a) { m0 += sp[a] * xv[a].x; m1 += sp[a] * xv[a].y; }
    m0 *= inv; m1 *= inv;

    ushort4v hb;
    hb.x = f2bf(hv.x); hb.y = f2bf(hv.y); hb.z = f2bf(hv.z); hb.w = f2bf(hv.w);
    *(ushort4v*)(Hb + (size_t)row * H_SZ + 4 * lane) = hb;
    ushort2v x1b; x1b.x = f2bf(x1v.x); x1b.y = f2bf(x1v.y);
    *(ushort2v*)(A1x + (size_t)row * E_SZ + 2 * lane) = x1b;
    ushort2v mb; mb.x = f2bf(m0); mb.y = f2bf(m1);
    *(ushort2v*)(A2x + (size_t)row * E_SZ + 2 * lane) = mb;
}

// ---------------- Kernel 2: weight pack: Wt[nn][k], nn = hcb*256 + g*32 + hc -
__global__ __launch_bounds__(256) void pack_w(Ptr8 ws, unsigned short* __restrict__ Wt)
{
    const int g = blockIdx.z, nt = blockIdx.y, kt = blockIdx.x;
    __shared__ float tile[64][65];
    const float* W = ws.p[g];
    const int c = threadIdx.x & 63, r0 = threadIdx.x >> 6;
    #pragma unroll
    for (int i = 0; i < 16; ++i) {
        int r = r0 + 4 * i;
        tile[r][c] = W[(size_t)(kt * 64 + r) * H_SZ + nt * 64 + c];
    }
    __syncthreads();
    #pragma unroll
    for (int i = 0; i < 16; ++i) {
        int rr = r0 + 4 * i;
        const int hcol = nt * 64 + rr;
        const int nn = ((hcol >> 5) << 8) + g * 32 + (hcol & 31);
        Wt[(size_t)nn * K_SZ + kt * 64 + c] = f2bf(tile[c][rr]);
    }
}

// ---------------- Kernel 3: BK=32 dbuf GEMM, 2 blk/CU + fast LSTM epilogue --
// Grid 1024 x 512thr, 64KB LDS -> 2 blocks/CU (16 waves/CU cross-block TLP).
// Block = 128 rows x 256 gcols. 8 waves 2Mx4N, wave 64x64 acc[4][4]. BK=32,
// 12 K-steps, double-buffered 2x32KB, 1 barrier/step. A/B in k-major subtile
// layout [kslot][row][16B]: ds_reads 256B-contiguous -> conflict-free, no swz.
__global__ __launch_bounds__(512, 4) void gemm_ep(
    const unsigned short* __restrict__ Hb, const unsigned short* __restrict__ A1x,
    const unsigned short* __restrict__ A2x, const unsigned short* __restrict__ Wt,
    Ptr8 bias, const float* __restrict__ c1, const float* __restrict__ c2,
    float* __restrict__ out)
{
    __shared__ char smem[65536];   // 2 x [A 16K | B 16K]; whole 64K = epilogue gf
    const int tid = threadIdx.x, w = tid >> 6, lane = tid & 63;
    const int d = blockIdx.x;
    // XCD-aware (bijective for 1024 = 8*128): XCD owns 16 contiguous rbs.
    const int rb  = (d & 7) * 16 + (d >> 6);
    const int hcb = (d >> 3) & 7;
    const int row0 = rb * 128, hcol0 = hcb * 32;
    const int fr = lane & 15, hi = lane >> 4;
    const int wM = w >> 2, wN = w & 3;

    const unsigned short* Bpan = Wt + (size_t)hcb * 256 * K_SZ;
    const int hcin = tid & 31, rgrp = tid >> 5;     // epilogue indices

    float bia[8];
    #pragma unroll
    for (int g = 0; g < 8; ++g) bia[g] = bias.p[g][hcol0 + hcin];

    auto glds = [&](const unsigned short* src, int dstoff) {
        __builtin_amdgcn_global_load_lds(
            (const __attribute__((address_space(1))) unsigned int*)src,
            (__attribute__((address_space(3))) unsigned int*)(smem + dstoff), 16, 0, 0);
    };
    // stage K-step ks (k in [ks*32, ks*32+32)) into buffer b.
    // Layouts: A [kslot4][R128][16B] (@0; x-step: A1x@0, A2x@8K), B [kslot4][C256][16B] @16K
    auto stage = [&](int ks, int b) {
        const int bufb = b * 32768;
        #pragma unroll
        for (int j = 0; j < 2; ++j) {            // B: 16KB = 2 wave-passes
            const int o = j * 8192 + w * 1024 + lane * 16;
            const int kslot = o >> 12, C = (o >> 4) & 255;
            glds(Bpan + (size_t)C * K_SZ + ks * 32 + kslot * 8,
                 bufb + 16384 + j * 8192 + w * 1024);
        }
        const int o = w * 1024 + lane * 16;      // A: 8KB per panel = 1 pass
        const int kslot = o >> 11, R = (o >> 4) & 127;
        if (ks < 8) {                            // shared h panel
            glds(Hb + (size_t)(row0 + R) * H_SZ + ks * 32 + kslot * 8,
                 bufb + w * 1024);
        } else {                                 // split x panels
            const int ko = (ks - 8) * 32 + kslot * 8;
            glds(A1x + (size_t)(row0 + R) * E_SZ + ko, bufb + w * 1024);
            glds(A2x + (size_t)(row0 + R) * E_SZ + ko, bufb + 8192 + w * 1024);
        }
    };

    f32x4 acc[4][4];
    #pragma unroll
    for (int mi = 0; mi < 4; ++mi)
        #pragma unroll
        for (int ni = 0; ni < 4; ++ni) acc[mi][ni] = (f32x4){0.f, 0.f, 0.f, 0.f};

    stage(0, 0);
    for (int ks = 0; ks < 12; ++ks) {
        __syncthreads();                         // drains stage(ks)
        if (ks < 11) stage(ks + 1, (ks + 1) & 1);   // flies under compute below
        const char* bb = smem + (ks & 1) * 32768;
        const int apo = (ks >= 8 && wN >= 2) ? 8192 : 0;
        short8v af[4], bf[4];
        #pragma unroll
        for (int mi = 0; mi < 4; ++mi) {
            const int R = wM * 64 + mi * 16 + fr;
            af[mi] = *(const short8v*)(bb + apo + hi * 2048 + R * 16);
        }
        #pragma unroll
        for (int ni = 0; ni < 4; ++ni) {
            const int C = wN * 64 + ni * 16 + fr;
            bf[ni] = *(const short8v*)(bb + 16384 + hi * 4096 + C * 16);
        }
        #pragma unroll
        for (int mi = 0; mi < 4; ++mi)
            #pragma unroll
            for (int ni = 0; ni < 4; ++ni)
                acc[mi][ni] = __builtin_amdgcn_mfma_f32_16x16x32_bf16(
                    af[mi], bf[ni], acc[mi][ni], 0, 0, 0);
    }

    // ---- epilogue operands (latency hides under exchange barriers) ----
    float c1p[2][4], c2p[2][4];
    #pragma unroll
    for (int p = 0; p < 2; ++p)
        #pragma unroll
        for (int rr = 0; rr < 4; ++rr) {
            const int R = p * 64 + rgrp * 4 + rr;
            c1p[p][rr] = c1[(size_t)(row0 + R) * H_SZ + hcol0 + hcin];
            c2p[p][rr] = c2[(size_t)(row0 + R) * H_SZ + hcol0 + hcin];
        }

    // ---- epilogue: two 64-row phases through the 64KB buffer ----
    float* gf = (float*)smem;                    // [8 g][64 r][32 c], parity-rot
    #pragma unroll
    for (int p = 0; p < 2; ++p) {
        __syncthreads();
        if (wM == p) {
            #pragma unroll
            for (int mi = 0; mi < 4; ++mi)
                #pragma unroll
                for (int ni = 0; ni < 4; ++ni)
                    #pragma unroll
                    for (int j = 0; j < 4; ++j) {
                        const int Rl2 = mi * 16 + hi * 4 + j;          // 0..63
                        const int g   = wN * 2 + (ni >> 1);
                        const int hc  = (ni & 1) * 16 + fr;
                        const int hcr = (hc + (((Rl2 >> 2) & 1) << 4)) & 31;
                        gf[(g * 64 + Rl2) * 32 + hcr] = acc[mi][ni][j];
                    }
        }
        __syncthreads();
        #pragma unroll
        for (int rr = 0; rr < 4; ++rr) {
            const int Rl2 = rgrp * 4 + rr;
            const int hcr = (hcin + (((Rl2 >> 2) & 1) << 4)) & 31;
            float G[8];
            #pragma unroll
            for (int g = 0; g < 8; ++g) G[g] = gf[(g * 64 + Rl2) * 32 + hcr] + bia[g];

            const float f1  = sigm_fast(G[0]);
            const float i1  = sigm_fast(G[1]);
            const float c1t = tanh_fast(G[2]);
            const float f2  = sigm_fast(G[4]);
            const float i2  = sigm_fast(G[5]);
            const float c2t = tanh_fast(G[6]);
            const float c1n = f1 * c1p[p][rr] + i1 * c1t;
            const float c2n = f2 * c2p[p][rr] + i2 * c2t;
            const float g0  = sigm_fast(G[3] - G[7]);    // e1/(e1+e2)
            const float th1 = tanh_fast(c1n);
            const float th2 = tanh_fast(c2n);
            const float hn  = th2 + g0 * (th1 - th2);

            const size_t o0 = (size_t)(row0 + p * 64 + Rl2) * H_SZ + hcol0 + hcin;
            out[o0]          = hn;
            out[BH + o0]     = c1n;
            out[2 * BH + o0] = c2n;
        }
    }
}

// ---------------- host ----------------
extern "C" void kernel_launch(void* const* d_in, const int* in_sizes, int n_in,
                              void* d_out, int out_size, void* d_ws, size_t ws_size,
                              hipStream_t stream)
{
    const float* x1 = (const float*)d_in[0];
    const float* x2 = (const float*)d_in[1];
    const float* h  = (const float*)d_in[2];
    const float* c1 = (const float*)d_in[3];
    const float* c2 = (const float*)d_in[4];
    const float* wa = (const float*)d_in[21];

    // gate order: 0..3 = cell1 {f,i,c,o}; 4..7 = cell2 {f,i,c,o}
    Ptr8 wptr, bptr;
    wptr.p[0] = (const float*)d_in[5];  wptr.p[1] = (const float*)d_in[9];
    wptr.p[2] = (const float*)d_in[13]; wptr.p[3] = (const float*)d_in[17];
    wptr.p[4] = (const float*)d_in[6];  wptr.p[5] = (const float*)d_in[10];
    wptr.p[6] = (const float*)d_in[14]; wptr.p[7] = (const float*)d_in[18];
    bptr.p[0] = (const float*)d_in[7];  bptr.p[1] = (const float*)d_in[11];
    bptr.p[2] = (const float*)d_in[15]; bptr.p[3] = (const float*)d_in[19];
    bptr.p[4] = (const float*)d_in[8];  bptr.p[5] = (const float*)d_in[12];
    bptr.p[6] = (const float*)d_in[16]; bptr.p[7] = (const float*)d_in[20];

    char* ws = (char*)d_ws;
    unsigned short* Hb  = (unsigned short*)(ws);              // 8.4 MB
    unsigned short* A1x = (unsigned short*)(ws + 8388608);    // 4.2 MB
    unsigned short* A2x = (unsigned short*)(ws + 12582912);   // 4.2 MB
    unsigned short* Wt  = (unsigned short*)(ws + 16777216);   // 1.6 MB

    pack_w<<<dim3(6, 4, 8), 256, 0, stream>>>(wptr, Wt);
    attn_pack<<<B_SZ / 4, 256, 0, stream>>>(x1, x2, h, wa, Hb, A1x, A2x);
    gemm_ep<<<1024, 512, 0, stream>>>(Hb, A1x, A2x, Wt, bptr, c1, c2, (float*)d_out);
}

// Round 12
// 121.146 us; speedup vs baseline: 1.0917x; 1.0917x over previous
//
#include <hip/hip_runtime.h>
#include <hip/hip_bf16.h>

#define B_SZ 16384
#define E_SZ 128
#define H_SZ 256
#define A_SZ 20
#define K_SZ 384           // H + E
#define BH   (B_SZ * H_SZ) // 4194304

typedef __attribute__((ext_vector_type(8))) short  short8v;
typedef __attribute__((ext_vector_type(4))) float  f32x4;
typedef __attribute__((ext_vector_type(2))) float  f32x2;
typedef __attribute__((ext_vector_type(4))) unsigned short ushort4v;
typedef __attribute__((ext_vector_type(2))) unsigned short ushort2v;

__device__ __forceinline__ unsigned short f2bf(float f) {
    union { float f; unsigned u; } v; v.f = f;
    unsigned r = v.u + 0x7fffu + ((v.u >> 16) & 1u);   // RNE
    return (unsigned short)(r >> 16);
}

__device__ __forceinline__ float wsum(float v) {
    #pragma unroll
    for (int off = 32; off > 0; off >>= 1) v += __shfl_xor(v, off, 64);
    return v;
}

// fast epilogue math: v_exp (TRANS pipe) + v_rcp, ~6 instr vs ~50 for libm
__device__ __forceinline__ float tanh_fast(float x) {
    float cx = fminf(fmaxf(x, -15.f), 15.f);
    float t  = __expf(2.f * cx);                  // e^{2x} <= e^30, no inf
    return (t - 1.f) * __builtin_amdgcn_rcpf(t + 1.f);
}
__device__ __forceinline__ float sigm_fast(float x) {
    float cx = fminf(fmaxf(x, -30.f), 30.f);
    return __builtin_amdgcn_rcpf(1.f + __expf(-cx));
}

struct Ptr8 { const float* p[8]; };

// ---------------- Kernel 1: attention + bf16 pack: Hb=[h], A1x=[x1], A2x=[x2m]
__global__ __launch_bounds__(256) void attn_pack(
    const float* __restrict__ x1, const float* __restrict__ x2,
    const float* __restrict__ h,  const float* __restrict__ wa,
    unsigned short* __restrict__ Hb, unsigned short* __restrict__ A1x,
    unsigned short* __restrict__ A2x)
{
    const int row  = blockIdx.x * 4 + (threadIdx.x >> 6);
    const int lane = threadIdx.x & 63;

    const f32x4 hv   = *(const f32x4*)(h  + (size_t)row * H_SZ + 4 * lane);
    const f32x2 x1v  = *(const f32x2*)(x1 + (size_t)row * E_SZ + 2 * lane);
    const f32x4 wah  = *(const f32x4*)(wa + 4 * lane);
    const f32x2 wax1 = *(const f32x2*)(wa + H_SZ + 2 * lane);
    const f32x2 wax2 = *(const f32x2*)(wa + H_SZ + E_SZ + 2 * lane);

    float base = hv.x * wah.x + hv.y * wah.y + hv.z * wah.z + hv.w * wah.w
               + x1v.x * wax1.x + x1v.y * wax1.y;

    f32x2 xv[A_SZ];
    float sp[A_SZ];
    const float* x2r = x2 + (size_t)row * A_SZ * E_SZ;
    #pragma unroll
    for (int a = 0; a < A_SZ; ++a) {
        xv[a] = *(const f32x2*)(x2r + a * E_SZ + 2 * lane);
        sp[a] = xv[a].x * wax2.x + xv[a].y * wax2.y;
    }

    base = wsum(base);
    #pragma unroll
    for (int a = 0; a < A_SZ; ++a) sp[a] = wsum(sp[a]) + base;

    float mx = sp[0];
    #pragma unroll
    for (int a = 1; a < A_SZ; ++a) mx = fmaxf(mx, sp[a]);
    float s = 0.0f;
    #pragma unroll
    for (int a = 0; a < A_SZ; ++a) { sp[a] = __expf(sp[a] - mx); s += sp[a]; }
    const float inv = 1.0f / s;

    float m0 = 0.0f, m1 = 0.0f;
    #pragma unroll
    for (int a = 0; a < A_SZ; ++a) { m0 += sp[a] * xv[a].x; m1 += sp[a] * xv[a].y; }
    m0 *= inv; m1 *= inv;

    ushort4v hb;
    hb.x = f2bf(hv.x); hb.y = f2bf(hv.y); hb.z = f2bf(hv.z); hb.w = f2bf(hv.w);
    *(ushort4v*)(Hb + (size_t)row * H_SZ + 4 * lane) = hb;
    ushort2v x1b; x1b.x = f2bf(x1v.x); x1b.y = f2bf(x1v.y);
    *(ushort2v*)(A1x + (size_t)row * E_SZ + 2 * lane) = x1b;
    ushort2v mb; mb.x = f2bf(m0); mb.y = f2bf(m1);
    *(ushort2v*)(A2x + (size_t)row * E_SZ + 2 * lane) = mb;
}

// ---------------- Kernel 2: weight pack: Wt[nn][k], nn = hcb*256 + g*32 + hc -
__global__ __launch_bounds__(256) void pack_w(Ptr8 ws, unsigned short* __restrict__ Wt)
{
    const int g = blockIdx.z, nt = blockIdx.y, kt = blockIdx.x;
    __shared__ float tile[64][65];
    const float* W = ws.p[g];
    const int c = threadIdx.x & 63, r0 = threadIdx.x >> 6;
    #pragma unroll
    for (int i = 0; i < 16; ++i) {
        int r = r0 + 4 * i;
        tile[r][c] = W[(size_t)(kt * 64 + r) * H_SZ + nt * 64 + c];
    }
    __syncthreads();
    #pragma unroll
    for (int i = 0; i < 16; ++i) {
        int rr = r0 + 4 * i;
        const int hcol = nt * 64 + rr;
        const int nn = ((hcol >> 5) << 8) + g * 32 + (hcol & 31);
        Wt[(size_t)nn * K_SZ + kt * 64 + c] = f2bf(tile[c][rr]);
    }
}

#define WAITV(N) asm volatile("s_waitcnt vmcnt(" #N ")" ::: "memory")

// ---------------- Kernel 3: 2-phase/step counted-vmcnt GEMM + LSTM epilogue -
// Grid 1024 x 512thr, 128KB dbuf. Block = 128 rows x 256 gcols, 8 waves 2Mx4N,
// wave 64x64 acc[4][4], BK=64, 6 steps. k-major LDS layouts (conflict-free,
// imm-offset ds_reads). Per step: {issue next-B, WAITV(4), barrier, kk0 MFMA}
// {issue next-A, kk1 MFMA, barrier} -- loads stay in flight across barriers.
__global__ __launch_bounds__(512, 1) void gemm_ep(
    const unsigned short* __restrict__ Hb, const unsigned short* __restrict__ A1x,
    const unsigned short* __restrict__ A2x, const unsigned short* __restrict__ Wt,
    Ptr8 bias, const float* __restrict__ c1, const float* __restrict__ c2,
    float* __restrict__ out)
{
    __shared__ char smem[131072];   // 2 x [A 32K | B 32K]; whole 128K = epilogue gf
    const int tid = threadIdx.x, w = tid >> 6, lane = tid & 63;
    const int d = blockIdx.x;
    // XCD-aware (bijective for 1024 = 8*128): XCD owns 16 contiguous rbs.
    const int rb  = (d & 7) * 16 + (d >> 6);
    const int hcb = (d >> 3) & 7;
    const int row0 = rb * 128, hcol0 = hcb * 32;
    const int fr = lane & 15, hi = lane >> 4;
    const int wM = w >> 2, wN = w & 3;

    const unsigned short* Bpan = Wt + (size_t)hcb * 256 * K_SZ;
    const int hcin = tid & 31, rgrp = tid >> 5;     // epilogue indices

    // ---- epilogue operand prefetch (oldest vm ops; retire during prologue) --
    float c1p[8], c2p[8], bia[8];
    #pragma unroll
    for (int rr = 0; rr < 8; ++rr) {
        const int R = rgrp * 8 + rr;
        c1p[rr] = c1[(size_t)(row0 + R) * H_SZ + hcol0 + hcin];
        c2p[rr] = c2[(size_t)(row0 + R) * H_SZ + hcol0 + hcin];
    }
    #pragma unroll
    for (int g = 0; g < 8; ++g) bia[g] = bias.p[g][hcol0 + hcin];

    auto glds = [&](const unsigned short* src, int dstoff) {
        __builtin_amdgcn_global_load_lds(
            (const __attribute__((address_space(1))) unsigned int*)src,
            (__attribute__((address_space(3))) unsigned int*)(smem + dstoff), 16, 0, 0);
    };
    // k-major layouts in buffer b (b*65536):
    //   A h-steps: [kslot8][R128][16B] @0        (16KB; x-steps: A1x@0, A2x@16K)
    //   B:         [kslot8][C256][16B] @32768    (32KB)
    auto stageB = [&](int t, int b) {              // 4 glds/thread
        const int bufb = b * 65536;
        #pragma unroll
        for (int j = 0; j < 4; ++j) {
            const int o = j * 8192 + tid * 16;
            const int kslot = o >> 12, C = (o >> 4) & 255;
            glds(Bpan + (size_t)C * K_SZ + t * 64 + kslot * 8, bufb + 32768 + o);
        }
    };
    auto stageA = [&](int t, int b) {              // 2 (h) or 4 (x) glds/thread
        const int bufb = b * 65536;
        #pragma unroll
        for (int i = 0; i < 2; ++i) {
            const int o = i * 8192 + tid * 16;
            const int kslot = o >> 11, R = (o >> 4) & 127;
            if (t < 4) {
                glds(Hb + (size_t)(row0 + R) * H_SZ + t * 64 + kslot * 8, bufb + o);
            } else {
                const int k = (t - 4) * 64 + kslot * 8;
                glds(A1x + (size_t)(row0 + R) * E_SZ + k, bufb + o);
                glds(A2x + (size_t)(row0 + R) * E_SZ + k, bufb + 16384 + o);
            }
        }
    };

    f32x4 acc[4][4];
    #pragma unroll
    for (int mi = 0; mi < 4; ++mi)
        #pragma unroll
        for (int ni = 0; ni < 4; ++ni) acc[mi][ni] = (f32x4){0.f, 0.f, 0.f, 0.f};

    stageB(0, 0);
    stageA(0, 0);

    #pragma unroll
    for (int t = 0; t < 6; ++t) {
        const char* bb = smem + (t & 1) * 65536;
        const int apo = (t >= 4 && wN >= 2) ? 16384 : 0;
        // ---- phase A: issue next-B, counted wait, barrier, kk=0 compute ----
        if (t < 5) { stageB(t + 1, (t + 1) & 1); WAITV(4); }
        else       { WAITV(0); }
        __builtin_amdgcn_s_barrier();            // all waves' stage(t) landed
        {
            short8v af[4], bf[4];
            #pragma unroll
            for (int mi = 0; mi < 4; ++mi)
                af[mi] = *(const short8v*)(bb + apo + hi * 2048 +
                                           (wM * 64 + mi * 16 + fr) * 16);
            #pragma unroll
            for (int ni = 0; ni < 4; ++ni)
                bf[ni] = *(const short8v*)(bb + 32768 + hi * 4096 +
                                           (wN * 64 + ni * 16 + fr) * 16);
            __builtin_amdgcn_s_setprio(1);
            #pragma unroll
            for (int mi = 0; mi < 4; ++mi)
                #pragma unroll
                for (int ni = 0; ni < 4; ++ni)
                    acc[mi][ni] = __builtin_amdgcn_mfma_f32_16x16x32_bf16(
                        af[mi], bf[ni], acc[mi][ni], 0, 0, 0);
            __builtin_amdgcn_s_setprio(0);
        }
        // ---- phase B: issue next-A, kk=1 compute, end barrier ----
        if (t < 5) stageA(t + 1, (t + 1) & 1);
        {
            short8v af[4], bf[4];
            #pragma unroll
            for (int mi = 0; mi < 4; ++mi)
                af[mi] = *(const short8v*)(bb + apo + (4 + hi) * 2048 +
                                           (wM * 64 + mi * 16 + fr) * 16);
            #pragma unroll
            for (int ni = 0; ni < 4; ++ni)
                bf[ni] = *(const short8v*)(bb + 32768 + (4 + hi) * 4096 +
                                           (wN * 64 + ni * 16 + fr) * 16);
            __builtin_amdgcn_s_setprio(1);
            #pragma unroll
            for (int mi = 0; mi < 4; ++mi)
                #pragma unroll
                for (int ni = 0; ni < 4; ++ni)
                    acc[mi][ni] = __builtin_amdgcn_mfma_f32_16x16x32_bf16(
                        af[mi], bf[ni], acc[mi][ni], 0, 0, 0);
            __builtin_amdgcn_s_setprio(0);
        }
        __builtin_amdgcn_s_barrier();            // reads of buf[t&1] complete
    }

    // ---- epilogue: single 128-row exchange through all 128KB ----
    __syncthreads();
    float* gf = (float*)smem;                    // [8 g][128 r][32 hc], rot-swz
    #pragma unroll
    for (int mi = 0; mi < 4; ++mi)
        #pragma unroll
        for (int ni = 0; ni < 4; ++ni)
            #pragma unroll
            for (int j = 0; j < 4; ++j) {
                const int R   = wM * 64 + mi * 16 + hi * 4 + j;
                const int g   = wN * 2 + (ni >> 1);
                const int hc  = (ni & 1) * 16 + fr;
                const int hcr = (hc + (((R >> 2) & 3) << 3)) & 31;
                gf[(g * 128 + R) * 32 + hcr] = acc[mi][ni][j];
            }
    __syncthreads();

    #pragma unroll
    for (int rr = 0; rr < 8; ++rr) {
        const int R   = rgrp * 8 + rr;
        const int hcr = (hcin + (((R >> 2) & 3) << 3)) & 31;
        float G[8];
        #pragma unroll
        for (int g = 0; g < 8; ++g) G[g] = gf[(g * 128 + R) * 32 + hcr] + bia[g];

        const float f1  = sigm_fast(G[0]);
        const float i1  = sigm_fast(G[1]);
        const float c1t = tanh_fast(G[2]);
        const float f2  = sigm_fast(G[4]);
        const float i2  = sigm_fast(G[5]);
        const float c2t = tanh_fast(G[6]);
        const float c1n = f1 * c1p[rr] + i1 * c1t;
        const float c2n = f2 * c2p[rr] + i2 * c2t;
        const float g0  = sigm_fast(G[3] - G[7]);    // e1/(e1+e2)
        const float th1 = tanh_fast(c1n);
        const float th2 = tanh_fast(c2n);
        const float hn  = th2 + g0 * (th1 - th2);

        const size_t o0 = (size_t)(row0 + R) * H_SZ + hcol0 + hcin;
        out[o0]          = hn;
        out[BH + o0]     = c1n;
        out[2 * BH + o0] = c2n;
    }
}

// ---------------- host ----------------
extern "C" void kernel_launch(void* const* d_in, const int* in_sizes, int n_in,
                              void* d_out, int out_size, void* d_ws, size_t ws_size,
                              hipStream_t stream)
{
    const float* x1 = (const float*)d_in[0];
    const float* x2 = (const float*)d_in[1];
    const float* h  = (const float*)d_in[2];
    const float* c1 = (const float*)d_in[3];
    const float* c2 = (const float*)d_in[4];
    const float* wa = (const float*)d_in[21];

    // gate order: 0..3 = cell1 {f,i,c,o}; 4..7 = cell2 {f,i,c,o}
    Ptr8 wptr, bptr;
    wptr.p[0] = (const float*)d_in[5];  wptr.p[1] = (const float*)d_in[9];
    wptr.p[2] = (const float*)d_in[13]; wptr.p[3] = (const float*)d_in[17];
    wptr.p[4] = (const float*)d_in[6];  wptr.p[5] = (const float*)d_in[10];
    wptr.p[6] = (const float*)d_in[14]; wptr.p[7] = (const float*)d_in[18];
    bptr.p[0] = (const float*)d_in[7];  bptr.p[1] = (const float*)d_in[11];
    bptr.p[2] = (const float*)d_in[15]; bptr.p[3] = (const float*)d_in[19];
    bptr.p[4] = (const float*)d_in[8];  bptr.p[5] = (const float*)d_in[12];
    bptr.p[6] = (const float*)d_in[16]; bptr.p[7] = (const float*)d_in[20];

    char* ws = (char*)d_ws;
    unsigned short* Hb  = (unsigned short*)(ws);              // 8.4 MB
    unsigned short* A1x = (unsigned short*)(ws + 8388608);    // 4.2 MB
    unsigned short* A2x = (unsigned short*)(ws + 12582912);   // 4.2 MB
    unsigned short* Wt  = (unsigned short*)(ws + 16777216);   // 1.6 MB

    pack_w<<<dim3(6, 4, 8), 256, 0, stream>>>(wptr, Wt);
    attn_pack<<<B_SZ / 4, 256, 0, stream>>>(x1, x2, h, wa, Hb, A1x, A2x);
    gemm_ep<<<1024, 512, 0, stream>>>(Hb, A1x, A2x, Wt, bptr, c1, c2, (float*)d_out);
}

// Round 13
// 110.795 us; speedup vs baseline: 1.1937x; 1.0934x over previous
//
#include <hip/hip_runtime.h>
#include <hip/hip_bf16.h>

#define B_SZ 16384
#define E_SZ 128
#define H_SZ 256
#define A_SZ 20
#define K_SZ 384           // H + E
#define BH   (B_SZ * H_SZ) // 4194304

typedef __attribute__((ext_vector_type(8))) short  short8v;
typedef __attribute__((ext_vector_type(4))) float  f32x4;
typedef __attribute__((ext_vector_type(2))) float  f32x2;
typedef __attribute__((ext_vector_type(4))) unsigned short ushort4v;
typedef __attribute__((ext_vector_type(2))) unsigned short ushort2v;

__device__ __forceinline__ unsigned short f2bf(float f) {
    union { float f; unsigned u; } v; v.f = f;
    unsigned r = v.u + 0x7fffu + ((v.u >> 16) & 1u);   // RNE
    return (unsigned short)(r >> 16);
}

__device__ __forceinline__ float wsum(float v) {
    #pragma unroll
    for (int off = 32; off > 0; off >>= 1) v += __shfl_xor(v, off, 64);
    return v;
}

// fast epilogue math: v_exp (TRANS pipe) + v_rcp, ~6 instr vs ~50 for libm
__device__ __forceinline__ float tanh_fast(float x) {
    float cx = fminf(fmaxf(x, -15.f), 15.f);
    float t  = __expf(2.f * cx);                  // e^{2x} <= e^30, no inf
    return (t - 1.f) * __builtin_amdgcn_rcpf(t + 1.f);
}
__device__ __forceinline__ float sigm_fast(float x) {
    float cx = fminf(fmaxf(x, -30.f), 30.f);
    return __builtin_amdgcn_rcpf(1.f + __expf(-cx));
}

struct Ptr8 { const float* p[8]; };

// ---- Kernel 1: attention + bf16 pack (blocks < 4096) AND weight pack (rest)
// attn: Hb=[h], A1x=[x1], A2x=[x2m].  pack: Wt[nn][k], nn = hcb*256+g*32+hc.
__global__ __launch_bounds__(256) void attn_pack(
    const float* __restrict__ x1, const float* __restrict__ x2,
    const float* __restrict__ h,  const float* __restrict__ wa,
    Ptr8 ws,
    unsigned short* __restrict__ Hb, unsigned short* __restrict__ A1x,
    unsigned short* __restrict__ A2x, unsigned short* __restrict__ Wt)
{
    if (blockIdx.x >= 4096) {                    // ---- weight-pack branch ----
        const int p = blockIdx.x - 4096;         // 192 blocks = 6 kt x 4 nt x 8 g
        const int kt = p % 6, nt = (p / 6) & 3, g = p / 24;
        __shared__ float tile[64][65];
        const float* W = ws.p[g];
        const int c = threadIdx.x & 63, r0 = threadIdx.x >> 6;
        #pragma unroll
        for (int i = 0; i < 16; ++i) {
            int r = r0 + 4 * i;
            tile[r][c] = W[(size_t)(kt * 64 + r) * H_SZ + nt * 64 + c];
        }
        __syncthreads();
        #pragma unroll
        for (int i = 0; i < 16; ++i) {
            int rr = r0 + 4 * i;
            const int hcol = nt * 64 + rr;
            const int nn = ((hcol >> 5) << 8) + g * 32 + (hcol & 31);
            Wt[(size_t)nn * K_SZ + kt * 64 + c] = f2bf(tile[c][rr]);
        }
        return;
    }

    const int row  = blockIdx.x * 4 + (threadIdx.x >> 6);
    const int lane = threadIdx.x & 63;

    const f32x4 hv   = *(const f32x4*)(h  + (size_t)row * H_SZ + 4 * lane);
    const f32x2 x1v  = *(const f32x2*)(x1 + (size_t)row * E_SZ + 2 * lane);
    const f32x4 wah  = *(const f32x4*)(wa + 4 * lane);
    const f32x2 wax1 = *(const f32x2*)(wa + H_SZ + 2 * lane);
    const f32x2 wax2 = *(const f32x2*)(wa + H_SZ + E_SZ + 2 * lane);

    float base = hv.x * wah.x + hv.y * wah.y + hv.z * wah.z + hv.w * wah.w
               + x1v.x * wax1.x + x1v.y * wax1.y;

    f32x2 xv[A_SZ];
    float sp[A_SZ];
    const float* x2r = x2 + (size_t)row * A_SZ * E_SZ;
    #pragma unroll
    for (int a = 0; a < A_SZ; ++a) {
        xv[a] = *(const f32x2*)(x2r + a * E_SZ + 2 * lane);
        sp[a] = xv[a].x * wax2.x + xv[a].y * wax2.y;
    }

    base = wsum(base);
    #pragma unroll
    for (int a = 0; a < A_SZ; ++a) sp[a] = wsum(sp[a]) + base;

    float mx = sp[0];
    #pragma unroll
    for (int a = 1; a < A_SZ; ++a) mx = fmaxf(mx, sp[a]);
    float s = 0.0f;
    #pragma unroll
    for (int a = 0; a < A_SZ; ++a) { sp[a] = __expf(sp[a] - mx); s += sp[a]; }
    const float inv = 1.0f / s;

    float m0 = 0.0f, m1 = 0.0f;
    #pragma unroll
    for (int a = 0; a < A_SZ; ++a) { m0 += sp[a] * xv[a].x; m1 += sp[a] * xv[a].y; }
    m0 *= inv; m1 *= inv;

    ushort4v hb;
    hb.x = f2bf(hv.x); hb.y = f2bf(hv.y); hb.z = f2bf(hv.z); hb.w = f2bf(hv.w);
    *(ushort4v*)(Hb + (size_t)row * H_SZ + 4 * lane) = hb;
    ushort2v x1b; x1b.x = f2bf(x1v.x); x1b.y = f2bf(x1v.y);
    *(ushort2v*)(A1x + (size_t)row * E_SZ + 2 * lane) = x1b;
    ushort2v mb; mb.x = f2bf(m0); mb.y = f2bf(m1);
    *(ushort2v*)(A2x + (size_t)row * E_SZ + 2 * lane) = mb;
}

// ---- Kernel 2: BM=256 dbuf GEMM (m97 loop) + fast fused LSTM epilogue ------
// Grid 512 x 512thr, 128KB dbuf (2x64KB). Block = 256 rows x 256 gcols.
// 8 waves 2Mx4N, wave 128x64 (acc[8][4]). K: 4 h-steps BK=64 + 4 x-steps BK=32.
// k-major LDS layouts (conflict-free). R10's winning 1-barrier/step loop.
__global__ __launch_bounds__(512, 1) void gemm_ep(
    const unsigned short* __restrict__ Hb, const unsigned short* __restrict__ A1x,
    const unsigned short* __restrict__ A2x, const unsigned short* __restrict__ Wt,
    Ptr8 bias, const float* __restrict__ c1, const float* __restrict__ c2,
    float* __restrict__ out)
{
    __shared__ char smem[131072];   // 2 x 64KB K-buffers; whole 128KB = epilogue gf
    const int tid = threadIdx.x, w = tid >> 6, lane = tid & 63;
    const int d = blockIdx.x;
    // XCD-aware (bijective for 512 = 8*64): XCD owns 8 contiguous rbs x 8 hcb.
    const int li  = d >> 3;
    const int rb  = (d & 7) * 8 + (li >> 3);
    const int hcb = li & 7;
    const int row0 = rb * 256, hcol0 = hcb * 32;
    const int fr = lane & 15, hi = lane >> 4;
    const int wM = w >> 2, wN = w & 3;

    const unsigned short* Bpan = Wt + (size_t)hcb * 256 * K_SZ;
    const int hcin = tid & 31, rgrp = tid >> 5;     // epilogue indices

    float bia[8];
    #pragma unroll
    for (int g = 0; g < 8; ++g) bia[g] = bias.p[g][hcol0 + hcin];

    auto glds = [&](const unsigned short* src, int dstoff) {
        __builtin_amdgcn_global_load_lds(
            (const __attribute__((address_space(1))) unsigned int*)src,
            (__attribute__((address_space(3))) unsigned int*)(smem + dstoff), 16, 0, 0);
    };
    // Buffer b layouts (bufb = b*65536):
    //  h-step (t<4, BK=64): A=Hb [kslot8][R256][16B] @0 (32K); B [kslot8][C256][16B] @32K
    //  x-step (t>=4,BK=32): A1 [kslot4][R256][16B] @0 (16K); A2 @16K; B [kslot4][C256][16B] @32K
    auto stage = [&](int t, int b) {
        const int bufb = b * 65536;
        if (t < 4) {
            #pragma unroll
            for (int j = 0; j < 4; ++j) {        // B 32KB
                const int o = j * 8192 + tid * 16;
                const int kslot = o >> 12, C = (o >> 4) & 255;
                glds(Bpan + (size_t)C * K_SZ + t * 64 + kslot * 8, bufb + 32768 + o);
            }
            #pragma unroll
            for (int i = 0; i < 4; ++i) {        // A 32KB
                const int o = i * 8192 + tid * 16;
                const int kslot = o >> 12, R = (o >> 4) & 255;
                glds(Hb + (size_t)(row0 + R) * H_SZ + t * 64 + kslot * 8, bufb + o);
            }
        } else {
            const int kx = (t - 4) * 32;
            #pragma unroll
            for (int j = 0; j < 2; ++j) {        // B 16KB
                const int o = j * 8192 + tid * 16;
                const int kslot = o >> 12, C = (o >> 4) & 255;
                glds(Bpan + (size_t)C * K_SZ + 256 + kx + kslot * 8, bufb + 32768 + o);
            }
            #pragma unroll
            for (int i = 0; i < 2; ++i) {        // A1 16KB + A2 16KB
                const int o = i * 8192 + tid * 16;
                const int kslot = o >> 12, R = (o >> 4) & 255;
                glds(A1x + (size_t)(row0 + R) * E_SZ + kx + kslot * 8, bufb + o);
                glds(A2x + (size_t)(row0 + R) * E_SZ + kx + kslot * 8, bufb + 16384 + o);
            }
        }
    };

    f32x4 acc[8][4];
    #pragma unroll
    for (int mi = 0; mi < 8; ++mi)
        #pragma unroll
        for (int ni = 0; ni < 4; ++ni) acc[mi][ni] = (f32x4){0.f, 0.f, 0.f, 0.f};

    stage(0, 0);
    for (int t = 0; t < 8; ++t) {
        __syncthreads();                         // drains stage(t)
        if (t < 7) stage(t + 1, (t + 1) & 1);    // flies under compute below
        const char* bb = smem + (t & 1) * 65536;
        if (t < 4) {
            #pragma unroll
            for (int kk = 0; kk < 2; ++kk) {
                const int ks = (kk * 4 + hi) * 4096;
                short8v bf[4];
                #pragma unroll
                for (int ni = 0; ni < 4; ++ni)
                    bf[ni] = *(const short8v*)(bb + 32768 + ks +
                                               (wN * 64 + ni * 16 + fr) * 16);
                #pragma unroll
                for (int mi = 0; mi < 8; ++mi) {
                    const short8v af = *(const short8v*)(bb + ks +
                                               (wM * 128 + mi * 16 + fr) * 16);
                    #pragma unroll
                    for (int ni = 0; ni < 4; ++ni)
                        acc[mi][ni] = __builtin_amdgcn_mfma_f32_16x16x32_bf16(
                            af, bf[ni], acc[mi][ni], 0, 0, 0);
                }
            }
        } else {
            const int apo = (wN >= 2) ? 16384 : 0;
            const int ks = hi * 4096;
            short8v bf[4];
            #pragma unroll
            for (int ni = 0; ni < 4; ++ni)
                bf[ni] = *(const short8v*)(bb + 32768 + ks +
                                           (wN * 64 + ni * 16 + fr) * 16);
            #pragma unroll
            for (int mi = 0; mi < 8; ++mi) {
                const short8v af = *(const short8v*)(bb + apo + ks +
                                           (wM * 128 + mi * 16 + fr) * 16);
                #pragma unroll
                for (int ni = 0; ni < 4; ++ni)
                    acc[mi][ni] = __builtin_amdgcn_mfma_f32_16x16x32_bf16(
                        af, bf[ni], acc[mi][ni], 0, 0, 0);
            }
        }
    }

    // ---- epilogue: two 128-row phases through all 128KB ----
    float* gf = (float*)smem;                    // [8 g][128 r][32 hc], rot-swz
    #pragma unroll
    for (int p = 0; p < 2; ++p) {
        // phase-p epilogue operands (latency hides under barriers/exchange)
        float c1p[8], c2p[8];
        #pragma unroll
        for (int rr = 0; rr < 8; ++rr) {
            const int R = p * 128 + rgrp * 8 + rr;
            c1p[rr] = c1[(size_t)(row0 + R) * H_SZ + hcol0 + hcin];
            c2p[rr] = c2[(size_t)(row0 + R) * H_SZ + hcol0 + hcin];
        }
        __syncthreads();
        if (wM == p) {
            #pragma unroll
            for (int mi = 0; mi < 8; ++mi)
                #pragma unroll
                for (int ni = 0; ni < 4; ++ni)
                    #pragma unroll
                    for (int j = 0; j < 4; ++j) {
                        const int Rl  = mi * 16 + hi * 4 + j;          // 0..127
                        const int g   = wN * 2 + (ni >> 1);
                        const int hc  = (ni & 1) * 16 + fr;
                        const int hcr = (hc + (((Rl >> 2) & 3) << 3)) & 31;
                        gf[(g * 128 + Rl) * 32 + hcr] = acc[mi][ni][j];
                    }
        }
        __syncthreads();
        #pragma unroll
        for (int rr = 0; rr < 8; ++rr) {
            const int Rl  = rgrp * 8 + rr;
            const int hcr = (hcin + (((Rl >> 2) & 3) << 3)) & 31;
            float G[8];
            #pragma unroll
            for (int g = 0; g < 8; ++g) G[g] = gf[(g * 128 + Rl) * 32 + hcr] + bia[g];

            const float f1  = sigm_fast(G[0]);
            const float i1  = sigm_fast(G[1]);
            const float c1t = tanh_fast(G[2]);
            const float f2  = sigm_fast(G[4]);
            const float i2  = sigm_fast(G[5]);
            const float c2t = tanh_fast(G[6]);
            const float c1n = f1 * c1p[rr] + i1 * c1t;
            const float c2n = f2 * c2p[rr] + i2 * c2t;
            const float g0  = sigm_fast(G[3] - G[7]);    // e1/(e1+e2)
            const float th1 = tanh_fast(c1n);
            const float th2 = tanh_fast(c2n);
            const float hn  = th2 + g0 * (th1 - th2);

            const size_t o0 = (size_t)(row0 + p * 128 + Rl) * H_SZ + hcol0 + hcin;
            out[o0]          = hn;
            out[BH + o0]     = c1n;
            out[2 * BH + o0] = c2n;
        }
    }
}

// ---------------- host ----------------
extern "C" void kernel_launch(void* const* d_in, const int* in_sizes, int n_in,
                              void* d_out, int out_size, void* d_ws, size_t ws_size,
                              hipStream_t stream)
{
    const float* x1 = (const float*)d_in[0];
    const float* x2 = (const float*)d_in[1];
    const float* h  = (const float*)d_in[2];
    const float* c1 = (const float*)d_in[3];
    const float* c2 = (const float*)d_in[4];
    const float* wa = (const float*)d_in[21];

    // gate order: 0..3 = cell1 {f,i,c,o}; 4..7 = cell2 {f,i,c,o}
    Ptr8 wptr, bptr;
    wptr.p[0] = (const float*)d_in[5];  wptr.p[1] = (const float*)d_in[9];
    wptr.p[2] = (const float*)d_in[13]; wptr.p[3] = (const float*)d_in[17];
    wptr.p[4] = (const float*)d_in[6];  wptr.p[5] = (const float*)d_in[10];
    wptr.p[6] = (const float*)d_in[14]; wptr.p[7] = (const float*)d_in[18];
    bptr.p[0] = (const float*)d_in[7];  bptr.p[1] = (const float*)d_in[11];
    bptr.p[2] = (const float*)d_in[15]; bptr.p[3] = (const float*)d_in[19];
    bptr.p[4] = (const float*)d_in[8];  bptr.p[5] = (const float*)d_in[12];
    bptr.p[6] = (const float*)d_in[16]; bptr.p[7] = (const float*)d_in[20];

    char* ws = (char*)d_ws;
    unsigned short* Hb  = (unsigned short*)(ws);              // 8.4 MB
    unsigned short* A1x = (unsigned short*)(ws + 8388608);    // 4.2 MB
    unsigned short* A2x = (unsigned short*)(ws + 12582912);   // 4.2 MB
    unsigned short* Wt  = (unsigned short*)(ws + 16777216);   // 1.6 MB

    attn_pack<<<4096 + 192, 256, 0, stream>>>(x1, x2, h, wa, wptr,
                                              Hb, A1x, A2x, Wt);
    gemm_ep<<<512, 512, 0, stream>>>(Hb, A1x, A2x, Wt, bptr, c1, c2, (float*)d_out);
}

// Round 14
// 94.669 us; speedup vs baseline: 1.3970x; 1.1703x over previous
//
#include <hip/hip_runtime.h>
#include <hip/hip_bf16.h>

#define B_SZ 16384
#define E_SZ 128
#define H_SZ 256
#define A_SZ 20
#define K_SZ 384           // H + E
#define BH   (B_SZ * H_SZ) // 4194304

typedef __attribute__((ext_vector_type(8))) short  short8v;
typedef __attribute__((ext_vector_type(4))) float  f32x4;
typedef __attribute__((ext_vector_type(2))) float  f32x2;
typedef __attribute__((ext_vector_type(4))) unsigned short ushort4v;
typedef __attribute__((ext_vector_type(2))) unsigned short ushort2v;

__device__ __forceinline__ unsigned short f2bf(float f) {
    union { float f; unsigned u; } v; v.f = f;
    unsigned r = v.u + 0x7fffu + ((v.u >> 16) & 1u);   // RNE
    return (unsigned short)(r >> 16);
}

__device__ __forceinline__ float wsum(float v) {
    #pragma unroll
    for (int off = 32; off > 0; off >>= 1) v += __shfl_xor(v, off, 64);
    return v;
}

// fast epilogue math: v_exp (TRANS pipe) + v_rcp, ~6 instr vs ~50 for libm
__device__ __forceinline__ float tanh_fast(float x) {
    float cx = fminf(fmaxf(x, -15.f), 15.f);
    float t  = __expf(2.f * cx);                  // e^{2x} <= e^30, no inf
    return (t - 1.f) * __builtin_amdgcn_rcpf(t + 1.f);
}
__device__ __forceinline__ float sigm_fast(float x) {
    float cx = fminf(fmaxf(x, -30.f), 30.f);
    return __builtin_amdgcn_rcpf(1.f + __expf(-cx));
}

struct Ptr8 { const float* p[8]; };

// ---------------- Kernel 1: attention + bf16 pack: Hb=[h], A1x=[x1], A2x=[x2m]
__global__ __launch_bounds__(256) void attn_pack(
    const float* __restrict__ x1, const float* __restrict__ x2,
    const float* __restrict__ h,  const float* __restrict__ wa,
    unsigned short* __restrict__ Hb, unsigned short* __restrict__ A1x,
    unsigned short* __restrict__ A2x)
{
    const int row  = blockIdx.x * 4 + (threadIdx.x >> 6);
    const int lane = threadIdx.x & 63;

    const f32x4 hv   = *(const f32x4*)(h  + (size_t)row * H_SZ + 4 * lane);
    const f32x2 x1v  = *(const f32x2*)(x1 + (size_t)row * E_SZ + 2 * lane);
    const f32x4 wah  = *(const f32x4*)(wa + 4 * lane);
    const f32x2 wax1 = *(const f32x2*)(wa + H_SZ + 2 * lane);
    const f32x2 wax2 = *(const f32x2*)(wa + H_SZ + E_SZ + 2 * lane);

    float base = hv.x * wah.x + hv.y * wah.y + hv.z * wah.z + hv.w * wah.w
               + x1v.x * wax1.x + x1v.y * wax1.y;

    f32x2 xv[A_SZ];
    float sp[A_SZ];
    const float* x2r = x2 + (size_t)row * A_SZ * E_SZ;
    #pragma unroll
    for (int a = 0; a < A_SZ; ++a) {
        xv[a] = *(const f32x2*)(x2r + a * E_SZ + 2 * lane);
        sp[a] = xv[a].x * wax2.x + xv[a].y * wax2.y;
    }

    base = wsum(base);
    #pragma unroll
    for (int a = 0; a < A_SZ; ++a) sp[a] = wsum(sp[a]) + base;

    float mx = sp[0];
    #pragma unroll
    for (int a = 1; a < A_SZ; ++a) mx = fmaxf(mx, sp[a]);
    float s = 0.0f;
    #pragma unroll
    for (int a = 0; a < A_SZ; ++a) { sp[a] = __expf(sp[a] - mx); s += sp[a]; }
    const float inv = 1.0f / s;

    float m0 = 0.0f, m1 = 0.0f;
    #pragma unroll
    for (int a = 0; a < A_SZ; ++a) { m0 += sp[a] * xv[a].x; m1 += sp[a] * xv[a].y; }
    m0 *= inv; m1 *= inv;

    ushort4v hb;
    hb.x = f2bf(hv.x); hb.y = f2bf(hv.y); hb.z = f2bf(hv.z); hb.w = f2bf(hv.w);
    *(ushort4v*)(Hb + (size_t)row * H_SZ + 4 * lane) = hb;
    ushort2v x1b; x1b.x = f2bf(x1v.x); x1b.y = f2bf(x1v.y);
    *(ushort2v*)(A1x + (size_t)row * E_SZ + 2 * lane) = x1b;
    ushort2v mb; mb.x = f2bf(m0); mb.y = f2bf(m1);
    *(ushort2v*)(A2x + (size_t)row * E_SZ + 2 * lane) = mb;
}

// ---------------- Kernel 2: weight pack: Wt[nn][k], nn = hcb*256 + g*32 + hc -
__global__ __launch_bounds__(256) void pack_w(Ptr8 ws, unsigned short* __restrict__ Wt)
{
    const int g = blockIdx.z, nt = blockIdx.y, kt = blockIdx.x;
    __shared__ float tile[64][65];
    const float* W = ws.p[g];
    const int c = threadIdx.x & 63, r0 = threadIdx.x >> 6;
    #pragma unroll
    for (int i = 0; i < 16; ++i) {
        int r = r0 + 4 * i;
        tile[r][c] = W[(size_t)(kt * 64 + r) * H_SZ + nt * 64 + c];
    }
    __syncthreads();
    #pragma unroll
    for (int i = 0; i < 16; ++i) {
        int rr = r0 + 4 * i;
        const int hcol = nt * 64 + rr;
        const int nn = ((hcol >> 5) << 8) + g * 32 + (hcol & 31);
        Wt[(size_t)nn * K_SZ + kt * 64 + c] = f2bf(tile[c][rr]);
    }
}

// ---------------- Kernel 3: PERSISTENT dbuf GEMM + fast fused LSTM epilogue -
// Grid 256 (1 blk/CU) x 512thr. Each block: 4 tiles of 128 rows x 256 gcols,
// same row-panel (A/c L2-hot), hcb varies. R10's proven K-loop (BK=64, 6 steps,
// 2x64KB dbuf, XOR swizzle). Cross-tile pipeline: at t=5 stage next tile's t=0
// into buf0; epilogue runs from buf1 only while those loads fly.
__global__ __launch_bounds__(512, 1) void gemm_ep(
    const unsigned short* __restrict__ Hb, const unsigned short* __restrict__ A1x,
    const unsigned short* __restrict__ A2x, const unsigned short* __restrict__ Wt,
    Ptr8 bias, const float* __restrict__ c1, const float* __restrict__ c2,
    float* __restrict__ out)
{
    __shared__ char smem[131072];   // 2 x [A 32K | B 32K]; buf1 doubles as gf
    const int tid = threadIdx.x, w = tid >> 6, lane = tid & 63;
    const int xcd = blockIdx.x & 7, bi = blockIdx.x >> 3;   // bi 0..31
    const int fr = lane & 15, hi = lane >> 4;
    const int wM = w >> 2, wN = w & 3;
    const int lr = lane >> 3, sl = lane & 7;    // 8 rows x 8 16B-slots per glds
    const int hcin = tid & 31, rgrp = tid >> 5; // epilogue indices

    auto glds = [&](const unsigned short* src, int dstoff) {
        __builtin_amdgcn_global_load_lds(
            (const __attribute__((address_space(1))) unsigned int*)src,
            (__attribute__((address_space(3))) unsigned int*)(smem + dstoff), 16, 0, 0);
    };
    // stage K-step t of tile (BpanT,row0T) into buffer bsel (R10 verbatim)
    auto stage = [&](const unsigned short* BpanT, int row0T, int t, int bsel) {
        const int bufb = bsel * 65536;
        #pragma unroll
        for (int j = 0; j < 4; ++j) {            // B panel: 256 cols x 64 k
            const int C = j * 64 + w * 8 + lr;
            glds(BpanT + (size_t)C * K_SZ + t * 64 + ((sl ^ (C & 7)) << 3),
                 bufb + 32768 + j * 8192 + w * 1024);
        }
        if (t < 4) {                             // shared h panel: 128 x 64k
            #pragma unroll
            for (int i = 0; i < 2; ++i) {
                const int R = i * 64 + w * 8 + lr;
                glds(Hb + (size_t)(row0T + R) * H_SZ + t * 64 + ((sl ^ (R & 7)) << 3),
                     bufb + i * 8192 + w * 1024);
            }
        } else {                                 // split x panels
            const int ko = (t - 4) * 64;
            #pragma unroll
            for (int i = 0; i < 2; ++i) {
                const int R = i * 64 + w * 8 + lr;
                const int sw = (sl ^ (R & 7)) << 3;
                glds(A1x + (size_t)(row0T + R) * E_SZ + ko + sw,
                     bufb + i * 8192 + w * 1024);
                glds(A2x + (size_t)(row0T + R) * E_SZ + ko + sw,
                     bufb + 16384 + i * 8192 + w * 1024);
            }
        }
    };

    // tile jj of this XCD: hcb = jj&7 (varies fastest), rb = xcd*16 + (jj>>3)
    auto tile_coords = [&](int jj, int& row0T, int& hcol0T,
                           const unsigned short*& BpanT) {
        const int hcb = jj & 7, rb = xcd * 16 + (jj >> 3);
        row0T = rb * 128; hcol0T = hcb * 32;
        BpanT = Wt + (size_t)hcb * 256 * K_SZ;
    };

    int row0, hcol0; const unsigned short* Bpan;
    tile_coords(bi * 4, row0, hcol0, Bpan);
    stage(Bpan, row0, 0, 0);                     // prologue fill (once per block)

    for (int it = 0; it < 4; ++it) {
        tile_coords(bi * 4 + it, row0, hcol0, Bpan);
        int row0n = 0, hcol0n; const unsigned short* Bpann = nullptr;
        if (it < 3) tile_coords(bi * 4 + it + 1, row0n, hcol0n, Bpann);

        // per-tile epilogue operands (latency hides under K-loop)
        float bia[8], c1p[2][4], c2p[2][4];
        #pragma unroll
        for (int g = 0; g < 8; ++g) bia[g] = bias.p[g][hcol0 + hcin];
        #pragma unroll
        for (int p = 0; p < 2; ++p)
            #pragma unroll
            for (int rr = 0; rr < 4; ++rr) {
                const int R = p * 64 + rgrp * 4 + rr;
                c1p[p][rr] = c1[(size_t)(row0 + R) * H_SZ + hcol0 + hcin];
                c2p[p][rr] = c2[(size_t)(row0 + R) * H_SZ + hcol0 + hcin];
            }

        f32x4 acc[4][4];
        #pragma unroll
        for (int mi = 0; mi < 4; ++mi)
            #pragma unroll
            for (int ni = 0; ni < 4; ++ni) acc[mi][ni] = (f32x4){0.f, 0.f, 0.f, 0.f};

        for (int t = 0; t < 6; ++t) {
            __syncthreads();                     // drains stage(t)
            if (t < 5)      stage(Bpan,  row0,  t + 1, (t + 1) & 1);
            else if (it < 3) stage(Bpann, row0n, 0, 0);   // cross-tile prefetch
            const char* bb = smem + (t & 1) * 65536;
            const int apo = (t >= 4 && wN >= 2) ? 16384 : 0;
            #pragma unroll
            for (int kk = 0; kk < 2; ++kk) {
                short8v af[4], bf[4];
                #pragma unroll
                for (int mi = 0; mi < 4; ++mi) {
                    const int R = wM * 64 + mi * 16 + fr;
                    af[mi] = *(const short8v*)(bb + apo + R * 128 +
                                               ((((kk << 2) + hi) ^ (R & 7)) << 4));
                }
                #pragma unroll
                for (int ni = 0; ni < 4; ++ni) {
                    const int C = wN * 64 + ni * 16 + fr;
                    bf[ni] = *(const short8v*)(bb + 32768 + C * 128 +
                                               ((((kk << 2) + hi) ^ (C & 7)) << 4));
                }
                #pragma unroll
                for (int mi = 0; mi < 4; ++mi)
                    #pragma unroll
                    for (int ni = 0; ni < 4; ++ni)
                        acc[mi][ni] = __builtin_amdgcn_mfma_f32_16x16x32_bf16(
                            af[mi], bf[ni], acc[mi][ni], 0, 0, 0);
            }
        }

        // ---- epilogue: two 64-row phases through buf1 (64KB); buf0 holds
        //      the next tile's staged step-0 untouched ----
        float* gf = (float*)(smem + 65536);      // [8 g][64 r][32 hc], parity-rot
        #pragma unroll
        for (int p = 0; p < 2; ++p) {
            __syncthreads();
            if (wM == p) {
                #pragma unroll
                for (int mi = 0; mi < 4; ++mi)
                    #pragma unroll
                    for (int ni = 0; ni < 4; ++ni)
                        #pragma unroll
                        for (int j = 0; j < 4; ++j) {
                            const int Rl2 = mi * 16 + hi * 4 + j;      // 0..63
                            const int g   = wN * 2 + (ni >> 1);
                            const int hc  = (ni & 1) * 16 + fr;
                            const int hcr = (hc + (((Rl2 >> 2) & 1) << 4)) & 31;
                            gf[(g * 64 + Rl2) * 32 + hcr] = acc[mi][ni][j];
                        }
            }
            __syncthreads();
            #pragma unroll
            for (int rr = 0; rr < 4; ++rr) {
                const int Rl2 = rgrp * 4 + rr;
                const int hcr = (hcin + (((Rl2 >> 2) & 1) << 4)) & 31;
                float G[8];
                #pragma unroll
                for (int g = 0; g < 8; ++g)
                    G[g] = gf[(g * 64 + Rl2) * 32 + hcr] + bia[g];

                const float f1  = sigm_fast(G[0]);
                const float i1  = sigm_fast(G[1]);
                const float c1t = tanh_fast(G[2]);
                const float f2  = sigm_fast(G[4]);
                const float i2  = sigm_fast(G[5]);
                const float c2t = tanh_fast(G[6]);
                const float c1n = f1 * c1p[p][rr] + i1 * c1t;
                const float c2n = f2 * c2p[p][rr] + i2 * c2t;
                const float g0  = sigm_fast(G[3] - G[7]);    // e1/(e1+e2)
                const float th1 = tanh_fast(c1n);
                const float th2 = tanh_fast(c2n);
                const float hn  = th2 + g0 * (th1 - th2);

                const size_t o0 = (size_t)(row0 + p * 64 + Rl2) * H_SZ + hcol0 + hcin;
                out[o0]          = hn;
                out[BH + o0]     = c1n;
                out[2 * BH + o0] = c2n;
            }
        }
    }
}

// ---------------- host ----------------
extern "C" void kernel_launch(void* const* d_in, const int* in_sizes, int n_in,
                              void* d_out, int out_size, void* d_ws, size_t ws_size,
                              hipStream_t stream)
{
    const float* x1 = (const float*)d_in[0];
    const float* x2 = (const float*)d_in[1];
    const float* h  = (const float*)d_in[2];
    const float* c1 = (const float*)d_in[3];
    const float* c2 = (const float*)d_in[4];
    const float* wa = (const float*)d_in[21];

    // gate order: 0..3 = cell1 {f,i,c,o}; 4..7 = cell2 {f,i,c,o}
    Ptr8 wptr, bptr;
    wptr.p[0] = (const float*)d_in[5];  wptr.p[1] = (const float*)d_in[9];
    wptr.p[2] = (const float*)d_in[13]; wptr.p[3] = (const float*)d_in[17];
    wptr.p[4] = (const float*)d_in[6];  wptr.p[5] = (const float*)d_in[10];
    wptr.p[6] = (const float*)d_in[14]; wptr.p[7] = (const float*)d_in[18];
    bptr.p[0] = (const float*)d_in[7];  bptr.p[1] = (const float*)d_in[11];
    bptr.p[2] = (const float*)d_in[15]; bptr.p[3] = (const float*)d_in[19];
    bptr.p[4] = (const float*)d_in[8];  bptr.p[5] = (const float*)d_in[12];
    bptr.p[6] = (const float*)d_in[16]; bptr.p[7] = (const float*)d_in[20];

    char* ws = (char*)d_ws;
    unsigned short* Hb  = (unsigned short*)(ws);              // 8.4 MB
    unsigned short* A1x = (unsigned short*)(ws + 8388608);    // 4.2 MB
    unsigned short* A2x = (unsigned short*)(ws + 12582912);   // 4.2 MB
    unsigned short* Wt  = (unsigned short*)(ws + 16777216);   // 1.6 MB

    pack_w<<<dim3(6, 4, 8), 256, 0, stream>>>(wptr, Wt);
    attn_pack<<<B_SZ / 4, 256, 0, stream>>>(x1, x2, h, wa, Hb, A1x, A2x);
    gemm_ep<<<256, 512, 0, stream>>>(Hb, A1x, A2x, Wt, bptr, c1, c2, (float*)d_out);
}

// Round 15
// 88.680 us; speedup vs baseline: 1.4913x; 1.0675x over previous
//
#include <hip/hip_runtime.h>
#include <hip/hip_bf16.h>

#define B_SZ 16384
#define E_SZ 128
#define H_SZ 256
#define A_SZ 20
#define K_SZ 384           // H + E
#define BH   (B_SZ * H_SZ) // 4194304

typedef __attribute__((ext_vector_type(8))) short  short8v;
typedef __attribute__((ext_vector_type(4))) float  f32x4;
typedef __attribute__((ext_vector_type(2))) float  f32x2;
typedef __attribute__((ext_vector_type(4))) unsigned short ushort4v;
typedef __attribute__((ext_vector_type(2))) unsigned short ushort2v;

__device__ __forceinline__ unsigned short f2bf(float f) {
    union { float f; unsigned u; } v; v.f = f;
    unsigned r = v.u + 0x7fffu + ((v.u >> 16) & 1u);   // RNE
    return (unsigned short)(r >> 16);
}

__device__ __forceinline__ float wsum(float v) {
    #pragma unroll
    for (int off = 32; off > 0; off >>= 1) v += __shfl_xor(v, off, 64);
    return v;
}

// fast epilogue math: v_exp (TRANS pipe) + v_rcp, ~6 instr vs ~50 for libm
__device__ __forceinline__ float tanh_fast(float x) {
    float cx = fminf(fmaxf(x, -15.f), 15.f);
    float t  = __expf(2.f * cx);                  // e^{2x} <= e^30, no inf
    return (t - 1.f) * __builtin_amdgcn_rcpf(t + 1.f);
}
__device__ __forceinline__ float sigm_fast(float x) {
    float cx = fminf(fmaxf(x, -30.f), 30.f);
    return __builtin_amdgcn_rcpf(1.f + __expf(-cx));
}

struct Ptr8 { const float* p[8]; };

// ---- Kernel 1: attention+pack (blocks < 4096) AND weight pack (blocks >= 4096)
// attn: Hb=[h], A1x=[x1], A2x=[x2m].  pack: Wt[nn][k], nn = hcb*256+g*32+hc.
// The 192 pack blocks run concurrently with attn blocks -- their ~9MB traffic
// is absorbed into attn's BW envelope instead of a serial dispatch.
__global__ __launch_bounds__(256) void attn_pack(
    const float* __restrict__ x1, const float* __restrict__ x2,
    const float* __restrict__ h,  const float* __restrict__ wa,
    Ptr8 ws,
    unsigned short* __restrict__ Hb, unsigned short* __restrict__ A1x,
    unsigned short* __restrict__ A2x, unsigned short* __restrict__ Wt)
{
    if (blockIdx.x >= 4096) {                    // ---- weight-pack branch ----
        const int p = blockIdx.x - 4096;         // 192 blocks = 6 kt x 4 nt x 8 g
        const int kt = p % 6, nt = (p / 6) & 3, g = p / 24;
        __shared__ float tile[64][65];
        const float* W = ws.p[g];
        const int c = threadIdx.x & 63, r0 = threadIdx.x >> 6;
        #pragma unroll
        for (int i = 0; i < 16; ++i) {
            int r = r0 + 4 * i;
            tile[r][c] = W[(size_t)(kt * 64 + r) * H_SZ + nt * 64 + c];
        }
        __syncthreads();
        #pragma unroll
        for (int i = 0; i < 16; ++i) {
            int rr = r0 + 4 * i;
            const int hcol = nt * 64 + rr;
            const int nn = ((hcol >> 5) << 8) + g * 32 + (hcol & 31);
            Wt[(size_t)nn * K_SZ + kt * 64 + c] = f2bf(tile[c][rr]);
        }
        return;
    }

    const int row  = blockIdx.x * 4 + (threadIdx.x >> 6);
    const int lane = threadIdx.x & 63;

    const f32x4 hv   = *(const f32x4*)(h  + (size_t)row * H_SZ + 4 * lane);
    const f32x2 x1v  = *(const f32x2*)(x1 + (size_t)row * E_SZ + 2 * lane);
    const f32x4 wah  = *(const f32x4*)(wa + 4 * lane);
    const f32x2 wax1 = *(const f32x2*)(wa + H_SZ + 2 * lane);
    const f32x2 wax2 = *(const f32x2*)(wa + H_SZ + E_SZ + 2 * lane);

    float base = hv.x * wah.x + hv.y * wah.y + hv.z * wah.z + hv.w * wah.w
               + x1v.x * wax1.x + x1v.y * wax1.y;

    f32x2 xv[A_SZ];
    float sp[A_SZ];
    const float* x2r = x2 + (size_t)row * A_SZ * E_SZ;
    #pragma unroll
    for (int a = 0; a < A_SZ; ++a) {
        xv[a] = *(const f32x2*)(x2r + a * E_SZ + 2 * lane);
        sp[a] = xv[a].x * wax2.x + xv[a].y * wax2.y;
    }

    base = wsum(base);
    #pragma unroll
    for (int a = 0; a < A_SZ; ++a) sp[a] = wsum(sp[a]) + base;

    float mx = sp[0];
    #pragma unroll
    for (int a = 1; a < A_SZ; ++a) mx = fmaxf(mx, sp[a]);
    float s = 0.0f;
    #pragma unroll
    for (int a = 0; a < A_SZ; ++a) { sp[a] = __expf(sp[a] - mx); s += sp[a]; }
    const float inv = 1.0f / s;

    float m0 = 0.0f, m1 = 0.0f;
    #pragma unroll
    for (int a = 0; a < A_SZ; ++a) { m0 += sp[a] * xv[a].x; m1 += sp[a] * xv[a].y; }
    m0 *= inv; m1 *= inv;

    ushort4v hb;
    hb.x = f2bf(hv.x); hb.y = f2bf(hv.y); hb.z = f2bf(hv.z); hb.w = f2bf(hv.w);
    *(ushort4v*)(Hb + (size_t)row * H_SZ + 4 * lane) = hb;
    ushort2v x1b; x1b.x = f2bf(x1v.x); x1b.y = f2bf(x1v.y);
    *(ushort2v*)(A1x + (size_t)row * E_SZ + 2 * lane) = x1b;
    ushort2v mb; mb.x = f2bf(m0); mb.y = f2bf(m1);
    *(ushort2v*)(A2x + (size_t)row * E_SZ + 2 * lane) = mb;
}

// ---------------- Kernel 2: PERSISTENT dbuf GEMM + fast fused LSTM epilogue -
// Grid 256 (1 blk/CU) x 512thr. Each block: 4 tiles of 128 rows x 256 gcols,
// same row-panel (A/c L2-hot), hcb varies. R10's proven K-loop (BK=64, 6 steps,
// 2x64KB dbuf, XOR swizzle). Cross-tile pipeline: at t=5 stage next tile's t=0
// into buf0; epilogue runs from buf1 only while those loads fly.
__global__ __launch_bounds__(512, 1) void gemm_ep(
    const unsigned short* __restrict__ Hb, const unsigned short* __restrict__ A1x,
    const unsigned short* __restrict__ A2x, const unsigned short* __restrict__ Wt,
    Ptr8 bias, const float* __restrict__ c1, const float* __restrict__ c2,
    float* __restrict__ out)
{
    __shared__ char smem[131072];   // 2 x [A 32K | B 32K]; buf1 doubles as gf
    const int tid = threadIdx.x, w = tid >> 6, lane = tid & 63;
    const int xcd = blockIdx.x & 7, bi = blockIdx.x >> 3;   // bi 0..31
    const int fr = lane & 15, hi = lane >> 4;
    const int wM = w >> 2, wN = w & 3;
    const int lr = lane >> 3, sl = lane & 7;    // 8 rows x 8 16B-slots per glds
    const int hcin = tid & 31, rgrp = tid >> 5; // epilogue indices

    auto glds = [&](const unsigned short* src, int dstoff) {
        __builtin_amdgcn_global_load_lds(
            (const __attribute__((address_space(1))) unsigned int*)src,
            (__attribute__((address_space(3))) unsigned int*)(smem + dstoff), 16, 0, 0);
    };
    // stage K-step t of tile (BpanT,row0T) into buffer bsel (R10 verbatim)
    auto stage = [&](const unsigned short* BpanT, int row0T, int t, int bsel) {
        const int bufb = bsel * 65536;
        #pragma unroll
        for (int j = 0; j < 4; ++j) {            // B panel: 256 cols x 64 k
            const int C = j * 64 + w * 8 + lr;
            glds(BpanT + (size_t)C * K_SZ + t * 64 + ((sl ^ (C & 7)) << 3),
                 bufb + 32768 + j * 8192 + w * 1024);
        }
        if (t < 4) {                             // shared h panel: 128 x 64k
            #pragma unroll
            for (int i = 0; i < 2; ++i) {
                const int R = i * 64 + w * 8 + lr;
                glds(Hb + (size_t)(row0T + R) * H_SZ + t * 64 + ((sl ^ (R & 7)) << 3),
                     bufb + i * 8192 + w * 1024);
            }
        } else {                                 // split x panels
            const int ko = (t - 4) * 64;
            #pragma unroll
            for (int i = 0; i < 2; ++i) {
                const int R = i * 64 + w * 8 + lr;
                const int sw = (sl ^ (R & 7)) << 3;
                glds(A1x + (size_t)(row0T + R) * E_SZ + ko + sw,
                     bufb + i * 8192 + w * 1024);
                glds(A2x + (size_t)(row0T + R) * E_SZ + ko + sw,
                     bufb + 16384 + i * 8192 + w * 1024);
            }
        }
    };

    // tile jj of this XCD: hcb = jj&7 (varies fastest), rb = xcd*16 + (jj>>3)
    auto tile_coords = [&](int jj, int& row0T, int& hcol0T,
                           const unsigned short*& BpanT) {
        const int hcb = jj & 7, rb = xcd * 16 + (jj >> 3);
        row0T = rb * 128; hcol0T = hcb * 32;
        BpanT = Wt + (size_t)hcb * 256 * K_SZ;
    };

    int row0, hcol0; const unsigned short* Bpan;
    tile_coords(bi * 4, row0, hcol0, Bpan);
    stage(Bpan, row0, 0, 0);                     // prologue fill (once per block)

    for (int it = 0; it < 4; ++it) {
        tile_coords(bi * 4 + it, row0, hcol0, Bpan);
        int row0n = 0, hcol0n; const unsigned short* Bpann = nullptr;
        if (it < 3) tile_coords(bi * 4 + it + 1, row0n, hcol0n, Bpann);

        // per-tile epilogue operands (latency hides under K-loop)
        float bia[8], c1p[2][4], c2p[2][4];
        #pragma unroll
        for (int g = 0; g < 8; ++g) bia[g] = bias.p[g][hcol0 + hcin];
        #pragma unroll
        for (int p = 0; p < 2; ++p)
            #pragma unroll
            for (int rr = 0; rr < 4; ++rr) {
                const int R = p * 64 + rgrp * 4 + rr;
                c1p[p][rr] = c1[(size_t)(row0 + R) * H_SZ + hcol0 + hcin];
                c2p[p][rr] = c2[(size_t)(row0 + R) * H_SZ + hcol0 + hcin];
            }

        f32x4 acc[4][4];
        #pragma unroll
        for (int mi = 0; mi < 4; ++mi)
            #pragma unroll
            for (int ni = 0; ni < 4; ++ni) acc[mi][ni] = (f32x4){0.f, 0.f, 0.f, 0.f};

        for (int t = 0; t < 6; ++t) {
            __syncthreads();                     // drains stage(t)
            if (t < 5)      stage(Bpan,  row0,  t + 1, (t + 1) & 1);
            else if (it < 3) stage(Bpann, row0n, 0, 0);   // cross-tile prefetch
            const char* bb = smem + (t & 1) * 65536;
            const int apo = (t >= 4 && wN >= 2) ? 16384 : 0;
            #pragma unroll
            for (int kk = 0; kk < 2; ++kk) {
                short8v af[4], bf[4];
                #pragma unroll
                for (int mi = 0; mi < 4; ++mi) {
                    const int R = wM * 64 + mi * 16 + fr;
                    af[mi] = *(const short8v*)(bb + apo + R * 128 +
                                               ((((kk << 2) + hi) ^ (R & 7)) << 4));
                }
                #pragma unroll
                for (int ni = 0; ni < 4; ++ni) {
                    const int C = wN * 64 + ni * 16 + fr;
                    bf[ni] = *(const short8v*)(bb + 32768 + C * 128 +
                                               ((((kk << 2) + hi) ^ (C & 7)) << 4));
                }
                #pragma unroll
                for (int mi = 0; mi < 4; ++mi)
                    #pragma unroll
                    for (int ni = 0; ni < 4; ++ni)
                        acc[mi][ni] = __builtin_amdgcn_mfma_f32_16x16x32_bf16(
                            af[mi], bf[ni], acc[mi][ni], 0, 0, 0);
            }
        }

        // ---- epilogue: two 64-row phases through buf1 (64KB); buf0 holds
        //      the next tile's staged step-0 untouched ----
        float* gf = (float*)(smem + 65536);      // [8 g][64 r][32 hc], parity-rot
        #pragma unroll
        for (int p = 0; p < 2; ++p) {
            __syncthreads();
            if (wM == p) {
                #pragma unroll
                for (int mi = 0; mi < 4; ++mi)
                    #pragma unroll
                    for (int ni = 0; ni < 4; ++ni)
                        #pragma unroll
                        for (int j = 0; j < 4; ++j) {
                            const int Rl2 = mi * 16 + hi * 4 + j;      // 0..63
                            const int g   = wN * 2 + (ni >> 1);
                            const int hc  = (ni & 1) * 16 + fr;
                            const int hcr = (hc + (((Rl2 >> 2) & 1) << 4)) & 31;
                            gf[(g * 64 + Rl2) * 32 + hcr] = acc[mi][ni][j];
                        }
            }
            __syncthreads();
            #pragma unroll
            for (int rr = 0; rr < 4; ++rr) {
                const int Rl2 = rgrp * 4 + rr;
                const int hcr = (hcin + (((Rl2 >> 2) & 1) << 4)) & 31;
                float G[8];
                #pragma unroll
                for (int g = 0; g < 8; ++g)
                    G[g] = gf[(g * 64 + Rl2) * 32 + hcr] + bia[g];

                const float f1  = sigm_fast(G[0]);
                const float i1  = sigm_fast(G[1]);
                const float c1t = tanh_fast(G[2]);
                const float f2  = sigm_fast(G[4]);
                const float i2  = sigm_fast(G[5]);
                const float c2t = tanh_fast(G[6]);
                const float c1n = f1 * c1p[p][rr] + i1 * c1t;
                const float c2n = f2 * c2p[p][rr] + i2 * c2t;
                const float g0  = sigm_fast(G[3] - G[7]);    // e1/(e1+e2)
                const float th1 = tanh_fast(c1n);
                const float th2 = tanh_fast(c2n);
                const float hn  = th2 + g0 * (th1 - th2);

                const size_t o0 = (size_t)(row0 + p * 64 + Rl2) * H_SZ + hcol0 + hcin;
                out[o0]          = hn;
                out[BH + o0]     = c1n;
                out[2 * BH + o0] = c2n;
            }
        }
    }
}

// ---------------- host ----------------
extern "C" void kernel_launch(void* const* d_in, const int* in_sizes, int n_in,
                              void* d_out, int out_size, void* d_ws, size_t ws_size,
                              hipStream_t stream)
{
    const float* x1 = (const float*)d_in[0];
    const float* x2 = (const float*)d_in[1];
    const float* h  = (const float*)d_in[2];
    const float* c1 = (const float*)d_in[3];
    const float* c2 = (const float*)d_in[4];
    const float* wa = (const float*)d_in[21];

    // gate order: 0..3 = cell1 {f,i,c,o}; 4..7 = cell2 {f,i,c,o}
    Ptr8 wptr, bptr;
    wptr.p[0] = (const float*)d_in[5];  wptr.p[1] = (const float*)d_in[9];
    wptr.p[2] = (const float*)d_in[13]; wptr.p[3] = (const float*)d_in[17];
    wptr.p[4] = (const float*)d_in[6];  wptr.p[5] = (const float*)d_in[10];
    wptr.p[6] = (const float*)d_in[14]; wptr.p[7] = (const float*)d_in[18];
    bptr.p[0] = (const float*)d_in[7];  bptr.p[1] = (const float*)d_in[11];
    bptr.p[2] = (const float*)d_in[15]; bptr.p[3] = (const float*)d_in[19];
    bptr.p[4] = (const float*)d_in[8];  bptr.p[5] = (const float*)d_in[12];
    bptr.p[6] = (const float*)d_in[16]; bptr.p[7] = (const float*)d_in[20];

    char* ws = (char*)d_ws;
    unsigned short* Hb  = (unsigned short*)(ws);              // 8.4 MB
    unsigned short* A1x = (unsigned short*)(ws + 8388608);    // 4.2 MB
    unsigned short* A2x = (unsigned short*)(ws + 12582912);   // 4.2 MB
    unsigned short* Wt  = (unsigned short*)(ws + 16777216);   // 1.6 MB

    attn_pack<<<4096 + 192, 256, 0, stream>>>(x1, x2, h, wa, wptr,
                                              Hb, A1x, A2x, Wt);
    gemm_ep<<<256, 512, 0, stream>>>(Hb, A1x, A2x, Wt, bptr, c1, c2, (float*)d_out);
}